// Round 9
// baseline (1453.614 us; speedup 1.0000x reference)
//
#include <hip/hip_runtime.h>

#define NN 256
#define BIGF 1e9f
#define NROWS_LDS 152                       // C rows cached in dynamic LDS (exact f32)
#define SMEM_BYTES (NROWS_LDS * 256 * 4)    // 155648 B <= 160 KiB
#define LDS_LIMIT (NROWS_LDS * 1024)

// One DPP min stage; old = x so any invalid-lane behavior is fmin(x,x) = identity.
template <int CTRL>
__device__ __forceinline__ float dpp_fmin(float x) {
    int t = __builtin_amdgcn_update_dpp(__float_as_int(x), __float_as_int(x),
                                        CTRL, 0xf, 0xf, false);
    return fminf(x, __int_as_float(t));
}

// Wave-64 min broadcast to all lanes through lane 63. (Verified rounds 4-6.)
__device__ __forceinline__ float wave_min_bcast(float x) {
    x = dpp_fmin<0x111>(x);  // row_shr:1
    x = dpp_fmin<0x112>(x);  // row_shr:2
    x = dpp_fmin<0x114>(x);  // row_shr:4
    x = dpp_fmin<0x118>(x);  // row_shr:8
    x = dpp_fmin<0x142>(x);  // row_bcast:15
    x = dpp_fmin<0x143>(x);  // row_bcast:31
    return __int_as_float(__builtin_amdgcn_readlane(__float_as_int(x), 63));
}

extern "C" __global__ __launch_bounds__(64)
void lap_solve(const float* __restrict__ C, float* __restrict__ out) {
    extern __shared__ float rowc[];          // [NROWS_LDS][256]
    const int lane = threadIdx.x;
    const int base = lane * 4;               // 1-based columns base+1..base+4
    const int boff = base * 4 - 1024;        // (row<<10)+boff = byte off of ((row-1)*256+base)

    {   // stage rows 1..NROWS_LDS of C into LDS (exact f32 copy)
        const float4* src = (const float4*)C;
        float4*       dst = (float4*)rowc;
        #pragma unroll 8
        for (int idx = lane; idx < NROWS_LDS * 64; idx += 64) dst[idx] = src[idx];
    }
    __syncthreads();

    // All per-column state in registers (statically indexed):
    float v0 = 0.f, v1 = 0.f, v2 = 0.f, v3 = 0.f;   // col duals v[j]
    float a0 = 0.f, a1 = 0.f, a2 = 0.f, a3 = 0.f;   // a_k = u[p_k]
    int   p0 = 0,  p1 = 0,  p2 = 0,  p3 = 0;        // matched row per col (0 = free)

    // Winner-row-sequence history (lane-striped: entry t lives in lane t&63 of
    // reg t>>6). h* = previous iteration (predictor), g* = being recorded.
    // Prediction is value-safe: a prefetch is consumed only when its address
    // equals the true winner's address.
    int h0 = 0, h1 = 0, h2 = 0, h3 = 0, h4 = 0;
    int g0 = 0, g1 = 0, g2 = 0, g3 = 0, g4 = 0;

    // prologue: row 1 (always LDS-resident)
    float4 r = *(const float4*)((const char*)rowc + ((1 << 10) + boff));

    for (int i = 1; i <= NN; ++i) {
        // m doubles as the masked key: used slots forced to BIGF, q guards
        // every write -> m behaves exactly like where(used, BIG, minv).
        float m0 = BIGF, m1 = BIGF, m2 = BIGF, m3 = BIGF;
        int   w0 = 0, w1 = 0, w2 = 0, w3 = 0;              // way (pred col)
        int   q0 = 0, q1 = 0, q2 = 0, q3 = 0;              // used flags
        float ui = 0.0f;            // u[i] accumulator (fresh row => 0)
        float u0 = 0.0f;            // u[i0] for current step (row i => 0)
        int   j0 = 0, jF = 0;

        for (int guard = 0; guard < 300; ++guard) {
            const int t   = guard + 1;       // step index (matches hist slot)
            const int seg = t >> 6, idx = t & 63;

            // ---- speculative prefetch of the predicted next row (issued
            // before the scan so its latency overlaps scan+DPP+ballot) ----
            int pred;
            if (seg == 0)      pred = __builtin_amdgcn_readlane(h0, idx);
            else if (seg == 1) pred = __builtin_amdgcn_readlane(h1, idx);
            else if (seg == 2) pred = __builtin_amdgcn_readlane(h2, idx);
            else if (seg == 3) pred = __builtin_amdgcn_readlane(h3, idx);
            else               pred = __builtin_amdgcn_readlane(h4, idx);
            float4 rpre;
            if (pred <= LDS_LIMIT)           // pred==0 -> LDS OOB -> returns 0 (safe)
                rpre = *(const float4*)((const char*)rowc + (pred + boff));
            else
                rpre = *(const float4*)((const char*)C + (pred + boff));

            // ---- scan: cur = (C1[i0][j] - u[i0]) - v[j] (exact ref op order) ----
            float c0 = (r.x - u0) - v0;
            float c1 = (r.y - u0) - v1;
            float c2 = (r.z - u0) - v2;
            float c3 = (r.w - u0) - v3;
            if (!q0 && c0 < m0) { m0 = c0; w0 = j0; }
            if (!q1 && c1 < m1) { m1 = c1; w1 = j0; }
            if (!q2 && c2 < m2) { m2 = c2; w2 = j0; }
            if (!q3 && c3 < m3) { m3 = c3; w3 = j0; }

            // local min (index pick runs parallel with the DPP chain)
            float bv = fminf(fminf(m0, m1), fminf(m2, m3));
            int   bk = (m0 == bv) ? 0 : (m1 == bv) ? 1 : (m2 == bv) ? 2 : 3;
            int   rc = (bk == 0) ? p0 : (bk == 1) ? p1 : (bk == 2) ? p2 : p3;
            float ra = (bk == 0) ? a0 : (bk == 1) ? a1 : (bk == 2) ? a2 : a3;
            int   bj = base + bk + 1;
            int   rcs = rc << 10;                   // candidate row byte-offset

            // wave min + lowest-lane winner = argmin first-index semantics
            float gmin = wave_min_bcast(bv);
            unsigned long long bal = __ballot(bv == gmin);
            int wl = (int)__builtin_ctzll(bal | 0x8000000000000000ULL);

            // FIRST: winner row offset -> resolve next row ASAP
            int rowoff = __builtin_amdgcn_readlane(rcs, wl);
            float4 rn;
            if (rowoff == pred)                 // hit: consume in-flight prefetch
                rn = rpre;
            else if (rowoff <= LDS_LIMIT)       // rowoff==0 -> OOB -> 0 (break follows)
                rn = *(const float4*)((const char*)rowc + (rowoff + boff));
            else
                rn = *(const float4*)((const char*)C + (rowoff + boff));

            // record this step's winner for next iteration's predictor
            // (lane idx takes rowoff; v_cndmask with a single SGPR operand)
            if (seg == 0)      { if (lane == idx) g0 = rowoff; }
            else if (seg == 1) { if (lane == idx) g1 = rowoff; }
            else if (seg == 2) { if (lane == idx) g2 = rowoff; }
            else if (seg == 3) { if (lane == idx) g3 = rowoff; }
            else               { if (lane == idx) g4 = rowoff; }

            // rest of the broadcast + dual updates hide under the load
            int   j1  = __builtin_amdgcn_readlane(bj, wl);
            float u0n = __int_as_float(__builtin_amdgcn_readlane(__float_as_int(ra), wl));

            float delta = gmin;                     // exact reference updates
            if (q0) { a0 += delta; v0 -= delta; } else { m0 -= delta; }
            if (q1) { a1 += delta; v1 -= delta; } else { m1 -= delta; }
            if (q2) { a2 += delta; v2 -= delta; } else { m2 -= delta; }
            if (q3) { a3 += delta; v3 -= delta; } else { m3 -= delta; }
            ui += delta;                            // col 0 (row i) used each step

            // winner becomes used from next step; force its key to BIG
            int oj = (j1 - 1) >> 2, sj = (j1 - 1) & 3;
            if (lane == oj) {
                if (sj == 0)      { q0 = 1; m0 = BIGF; }
                else if (sj == 1) { q1 = 1; m1 = BIGF; }
                else if (sj == 2) { q2 = 1; m2 = BIGF; }
                else              { q3 = 1; m3 = BIGF; }
            }

            j0 = j1; u0 = u0n; r = rn;
            if (rowoff == 0) { jF = j1; break; }    // winner column is free
        }

        // predictor handoff: this iteration's sequence becomes the forecast
        h0 = g0; h1 = g1; h2 = g2; h3 = g3; h4 = g4;

        // prefetch next outer iteration's row before the augment walk
        {
            int ni = (i < NN) ? (i + 1) : NN;
            int off = (ni << 10) + boff;
            if (ni <= NROWS_LDS) r = *(const float4*)((const char*)rowc + off);
            else                 r = *(const float4*)((const char*)C + off);
        }

        // augment: j is wave-uniform -> readlane (not ds_bpermute) per hop
        int j = jF;
        for (int g2w = 0; g2w < 300 && j != 0; ++g2w) {
            int oj = (j - 1) >> 2, sj = (j - 1) & 3;
            int wsel = (sj == 0) ? w0 : (sj == 1) ? w1 : (sj == 2) ? w2 : w3;
            int jn = __builtin_amdgcn_readlane(wsel, oj);
            int pn; float an;
            if (jn == 0) { pn = i; an = ui; }
            else {
                int on = (jn - 1) >> 2, sn = (jn - 1) & 3;
                int   ps = (sn == 0) ? p0 : (sn == 1) ? p1 : (sn == 2) ? p2 : p3;
                float as = (sn == 0) ? a0 : (sn == 1) ? a1 : (sn == 2) ? a2 : a3;
                pn = __builtin_amdgcn_readlane(ps, on);
                an = __int_as_float(__builtin_amdgcn_readlane(__float_as_int(as), on));
            }
            if (lane == oj) {
                if (sj == 0)      { p0 = pn; a0 = an; }
                else if (sj == 1) { p1 = pn; a1 = an; }
                else if (sj == 2) { p2 = pn; a2 = an; }
                else              { p3 = pn; a3 = an; }
            }
            j = jn;
        }
    }

    // emit 0/1 labelling: out[p[j]-1, j-1] = 1  (out pre-zeroed by memset)
    if (p0) out[(p0 - 1) * NN + base + 0] = 1.0f;
    if (p1) out[(p1 - 1) * NN + base + 1] = 1.0f;
    if (p2) out[(p2 - 1) * NN + base + 2] = 1.0f;
    if (p3) out[(p3 - 1) * NN + base + 3] = 1.0f;
}

extern "C" void kernel_launch(void* const* d_in, const int* in_sizes, int n_in,
                              void* d_out, int out_size, void* d_ws, size_t ws_size,
                              hipStream_t stream) {
    const float* C   = (const float*)d_in[0];
    float*       out = (float*)d_out;

    static_assert(SMEM_BYTES <= 160 * 1024, "LDS budget");
    (void)hipFuncSetAttribute((const void*)lap_solve,
                              hipFuncAttributeMaxDynamicSharedMemorySize,
                              SMEM_BYTES);

    (void)hipMemsetAsync(out, 0, NN * NN * sizeof(float), stream);
    lap_solve<<<dim3(1), dim3(64), SMEM_BYTES, stream>>>(C, out);
}

// Round 10
// 1014.018 us; speedup vs baseline: 1.4335x; 1.4335x over previous
//
#include <hip/hip_runtime.h>

#define NN 256
#define BIGF 1e9f
#define NROWS_LDS 152                       // C rows cached in dynamic LDS (exact f32)
#define SMEM_BYTES (NROWS_LDS * 256 * 4)    // 155648 B <= 160 KiB
#define LDS_LIMIT (NROWS_LDS * 1024)

// One DPP min stage; old = x so any invalid-lane behavior is fmin(x,x) = identity.
template <int CTRL>
__device__ __forceinline__ float dpp_fmin(float x) {
    int t = __builtin_amdgcn_update_dpp(__float_as_int(x), __float_as_int(x),
                                        CTRL, 0xf, 0xf, false);
    return fminf(x, __int_as_float(t));
}

// Wave-64 min broadcast to all lanes through lane 63. (Verified rounds 4-9.)
__device__ __forceinline__ float wave_min_bcast(float x) {
    x = dpp_fmin<0x111>(x);  // row_shr:1
    x = dpp_fmin<0x112>(x);  // row_shr:2
    x = dpp_fmin<0x114>(x);  // row_shr:4
    x = dpp_fmin<0x118>(x);  // row_shr:8
    x = dpp_fmin<0x142>(x);  // row_bcast:15
    x = dpp_fmin<0x143>(x);  // row_bcast:31
    return __int_as_float(__builtin_amdgcn_readlane(__float_as_int(x), 63));
}

extern "C" __global__ __launch_bounds__(64)
void lap_solve(const float* __restrict__ C, float* __restrict__ out) {
    extern __shared__ float rowc[];          // [NROWS_LDS][256]
    const int lane = threadIdx.x;
    const int base = lane * 4;               // 1-based columns base+1..base+4
    const int boff = base * 4 - 1024;        // (row<<10)+boff = byte off of ((row-1)*256+base)

    {   // stage rows 1..NROWS_LDS of C into LDS (exact f32 copy)
        const float4* src = (const float4*)C;
        float4*       dst = (float4*)rowc;
        #pragma unroll 8
        for (int idx = lane; idx < NROWS_LDS * 64; idx += 64) dst[idx] = src[idx];
    }
    __syncthreads();

    // All per-column state in registers (statically indexed):
    float v0 = 0.f, v1 = 0.f, v2 = 0.f, v3 = 0.f;   // col duals v[j]
    float a0 = 0.f, a1 = 0.f, a2 = 0.f, a3 = 0.f;   // a_k = u[p_k]
    int   p0 = 0,  p1 = 0,  p2 = 0,  p3 = 0;        // matched row per col (0 = free)

    // prologue: row 1 (always LDS-resident)
    float4 r = *(const float4*)((const char*)rowc + ((1 << 10) + boff));

    for (int i = 1; i <= NN; ++i) {
        // m is the masked key: used slots are set to BIGF at marking and then
        // drift as BIG - sum(delta) (unconditional subtraction below) — still
        // >> any real reduced cost, and every read of a used slot's m is
        // masked (scan q-guard, bv-min, ballot), so trajectory is bit-exact.
        float m0 = BIGF, m1 = BIGF, m2 = BIGF, m3 = BIGF;
        int   w0 = 0, w1 = 0, w2 = 0, w3 = 0;              // way (pred col)
        int   q0 = 0, q1 = 0, q2 = 0, q3 = 0;              // used flags
        float ui = 0.0f;            // u[i] accumulator (fresh row => 0)
        float u0 = 0.0f;            // u[i0] for current step (row i => 0)
        int   j0 = 0, jF = 0;

        for (int guard = 0; guard < 300; ++guard) {
            // cur = (C1[i0][j] - u[i0]) - v[j]  (exact reference op order)
            float c0 = (r.x - u0) - v0;
            float c1 = (r.y - u0) - v1;
            float c2 = (r.z - u0) - v2;
            float c3 = (r.w - u0) - v3;
            if (!q0 && c0 < m0) { m0 = c0; w0 = j0; }
            if (!q1 && c1 < m1) { m1 = c1; w1 = j0; }
            if (!q2 && c2 < m2) { m2 = c2; w2 = j0; }
            if (!q3 && c3 < m3) { m3 = c3; w3 = j0; }

            // local min (index pick runs parallel with the DPP chain)
            float bv = fminf(fminf(m0, m1), fminf(m2, m3));
            int   bk = (m0 == bv) ? 0 : (m1 == bv) ? 1 : (m2 == bv) ? 2 : 3;
            int   rc = (bk == 0) ? p0 : (bk == 1) ? p1 : (bk == 2) ? p2 : p3;
            float ra = (bk == 0) ? a0 : (bk == 1) ? a1 : (bk == 2) ? a2 : a3;
            // packed payload: row byte-offset (bits 10+) | column id (bits 0..9)
            // rc <= 256 -> rc<<10 disjoint from bj in [1,257]
            int   packed = (rc << 10) | (base + bk + 1);

            // wave min + lowest-lane winner = argmin first-index semantics
            float gmin = wave_min_bcast(bv);
            unsigned long long bal = __ballot(bv == gmin);
            int wl = (int)__builtin_ctzll(bal | 0x8000000000000000ULL);

            // ONE readlane gives row offset AND winner column
            int rdl    = __builtin_amdgcn_readlane(packed, wl);
            int rowoff = rdl & ~1023;
            int j1     = rdl & 1023;

            // issue next row load ASAP (rowoff==0 -> LDS OOB -> 0, break follows)
            float4 rn;
            if (rowoff <= LDS_LIMIT)
                rn = *(const float4*)((const char*)rowc + (rowoff + boff));
            else
                rn = *(const float4*)((const char*)C + (rowoff + boff));

            // winner's u[p] for next step's scan (hides under the load)
            float u0n = __int_as_float(__builtin_amdgcn_readlane(__float_as_int(ra), wl));

            float delta = gmin;                     // exact reference updates
            if (q0) { a0 += delta; v0 -= delta; }   // used: u[p]+=d, v-=d
            if (q1) { a1 += delta; v1 -= delta; }
            if (q2) { a2 += delta; v2 -= delta; }
            if (q3) { a3 += delta; v3 -= delta; }
            m0 -= delta;                            // unconditional: exact for
            m1 -= delta;                            // unused; masked drift for
            m2 -= delta;                            // used (never observed)
            m3 -= delta;
            ui += delta;                            // col 0 (row i) used each step

            // winner becomes used from next step; force its key to BIG.
            // (lane wl's own bk identifies the winning slot — same lane/slot
            // as the old (j1-1)>>2 / &3 derivation since j1 = 4*wl + bk + 1.)
            if (lane == wl) {
                if (bk == 0)      { q0 = 1; m0 = BIGF; }
                else if (bk == 1) { q1 = 1; m1 = BIGF; }
                else if (bk == 2) { q2 = 1; m2 = BIGF; }
                else              { q3 = 1; m3 = BIGF; }
            }

            j0 = j1; u0 = u0n; r = rn;
            if (rowoff == 0) { jF = j1; break; }    // winner column is free
        }

        // prefetch next outer iteration's row before the augment walk
        {
            int ni = (i < NN) ? (i + 1) : NN;
            int off = (ni << 10) + boff;
            if (ni <= NROWS_LDS) r = *(const float4*)((const char*)rowc + off);
            else                 r = *(const float4*)((const char*)C + off);
        }

        // augment: j is wave-uniform -> readlane per hop
        int j = jF;
        for (int g2w = 0; g2w < 300 && j != 0; ++g2w) {
            int oj = (j - 1) >> 2, sj = (j - 1) & 3;
            int wsel = (sj == 0) ? w0 : (sj == 1) ? w1 : (sj == 2) ? w2 : w3;
            int jn = __builtin_amdgcn_readlane(wsel, oj);
            int pn; float an;
            if (jn == 0) { pn = i; an = ui; }
            else {
                int on = (jn - 1) >> 2, sn = (jn - 1) & 3;
                int   ps = (sn == 0) ? p0 : (sn == 1) ? p1 : (sn == 2) ? p2 : p3;
                float as = (sn == 0) ? a0 : (sn == 1) ? a1 : (sn == 2) ? a2 : a3;
                pn = __builtin_amdgcn_readlane(ps, on);
                an = __int_as_float(__builtin_amdgcn_readlane(__float_as_int(as), on));
            }
            if (lane == oj) {
                if (sj == 0)      { p0 = pn; a0 = an; }
                else if (sj == 1) { p1 = pn; a1 = an; }
                else if (sj == 2) { p2 = pn; a2 = an; }
                else              { p3 = pn; a3 = an; }
            }
            j = jn;
        }
    }

    // emit 0/1 labelling: out[p[j]-1, j-1] = 1  (out pre-zeroed by memset)
    if (p0) out[(p0 - 1) * NN + base + 0] = 1.0f;
    if (p1) out[(p1 - 1) * NN + base + 1] = 1.0f;
    if (p2) out[(p2 - 1) * NN + base + 2] = 1.0f;
    if (p3) out[(p3 - 1) * NN + base + 3] = 1.0f;
}

extern "C" void kernel_launch(void* const* d_in, const int* in_sizes, int n_in,
                              void* d_out, int out_size, void* d_ws, size_t ws_size,
                              hipStream_t stream) {
    const float* C   = (const float*)d_in[0];
    float*       out = (float*)d_out;

    static_assert(SMEM_BYTES <= 160 * 1024, "LDS budget");
    (void)hipFuncSetAttribute((const void*)lap_solve,
                              hipFuncAttributeMaxDynamicSharedMemorySize,
                              SMEM_BYTES);

    (void)hipMemsetAsync(out, 0, NN * NN * sizeof(float), stream);
    lap_solve<<<dim3(1), dim3(64), SMEM_BYTES, stream>>>(C, out);
}